// Round 8
// baseline (718.469 us; speedup 1.0000x reference)
//
#include <hip/hip_runtime.h>
#include <stdint.h>
#include <math.h>

#define N_NODES 100000
#define N_EDGES 1600000

typedef __bf16 bf16_t;
typedef __attribute__((ext_vector_type(4))) __bf16 bf16x4;
typedef __attribute__((ext_vector_type(8))) __bf16 bf16x8;
typedef __attribute__((ext_vector_type(4))) float f32x4;
typedef __attribute__((ext_vector_type(2))) uint32_t u32x2;
typedef __attribute__((ext_vector_type(4))) uint32_t u32x4;

__device__ __forceinline__ f32x4 mfma16(bf16x8 a, bf16x8 b, f32x4 c) {
  return __builtin_amdgcn_mfma_f32_16x16x32_bf16(a, b, c, 0, 0, 0);
}

// ---------------- Threefry-2x32 (JAX-compatible) ----------------
__device__ __host__ __forceinline__ uint32_t rotl32(uint32_t v, int d) {
  return (v << d) | (v >> (32 - d));
}

__device__ __host__ __forceinline__ void threefry2x32(uint32_t k0, uint32_t k1,
                                                      uint32_t x0, uint32_t x1,
                                                      uint32_t& o0, uint32_t& o1) {
  uint32_t ks0 = k0, ks1 = k1, ks2 = k0 ^ k1 ^ 0x1BD11BDAu;
  x0 += ks0; x1 += ks1;
#define TF_R(r) { x0 += x1; x1 = rotl32(x1, r); x1 ^= x0; }
  TF_R(13) TF_R(15) TF_R(26) TF_R(6)
  x0 += ks1; x1 += ks2 + 1u;
  TF_R(17) TF_R(29) TF_R(16) TF_R(24)
  x0 += ks2; x1 += ks0 + 2u;
  TF_R(13) TF_R(15) TF_R(26) TF_R(6)
  x0 += ks0; x1 += ks1 + 3u;
  TF_R(17) TF_R(29) TF_R(16) TF_R(24)
  x0 += ks1; x1 += ks2 + 4u;
  TF_R(13) TF_R(15) TF_R(26) TF_R(6)
  x0 += ks2; x1 += ks0 + 5u;
#undef TF_R
  o0 = x0; o1 = x1;
}

// Partitionable-threefry dropout (JAX default): bits = o0^o1 of tf(key; 0, idx)
__device__ __forceinline__ float drop_scale(uint32_t idx, uint32_t k0, uint32_t k1) {
  uint32_t o0, o1;
  threefry2x32(k0, k1, 0u, idx, o0, o1);
  uint32_t bits = o0 ^ o1;
  float u = __uint_as_float((bits >> 9) | 0x3f800000u) - 1.0f;
  return (u < 0.5f) ? 2.0f : 0.0f;
}

// ---------------- Edge dtype detect ----------------
__global__ __launch_bounds__(256) void detect_kernel(const int* __restrict__ ei,
                                                     int* __restrict__ found_nonzero) {
  int idx = blockIdx.x * 256 + threadIdx.x;  // 0..2047
  size_t j = (size_t)idx * 781;              // < 1.6M
  if (ei[2 * j + 1] != 0) atomicOr(found_nonzero, 1);
}

__device__ __forceinline__ int edge_row(const int* ei, bool i32, int e) {
  return i32 ? ei[e] : ei[2 * (size_t)e];
}
__device__ __forceinline__ int edge_col(const int* ei, bool i32, int e) {
  return i32 ? ei[N_EDGES + e] : ei[2 * ((size_t)N_EDGES + (size_t)e)];
}

// ---------------- Graph preprocessing: counting-sort CSR build --------------
// Block-aggregated counting sort — LDS histograms + hierarchical scan give
// every block an EXCLUSIVE write range. Zero contended global atomics.
// Edge stream is compact u32 rows (erow); norm = dis[r]*dis[c] is recomputed
// in prop (bit-identical f32 mul). [r7 lesson: per-node source-sorting is a
// NULL for gather locality (FETCH unchanged to 0.1%) and costs ~35us — gone.]
#define BKT_SHIFT 8
#define NBKT 391        // ceil(100000/256) buckets of 256 dest nodes
#define BKT_CAP 6144    // max bucket size (mean 4092, sigma 64 -> +32 sigma)
#define EPB 8192        // edges per histogram/fill block
#define NBLK 196        // ceil(1.6M/8192)
#define SCAN_M (NBKT * NBLK)  // 76636

// Pass 1: per-block LDS histogram over buckets -> hist[bucket][block]
__global__ __launch_bounds__(256) void hist_kernel(const int* __restrict__ ei,
                                                   const int* __restrict__ flag,
                                                   int* __restrict__ hist) {
  __shared__ int h[NBKT];
  const int t = threadIdx.x, blk = blockIdx.x;
  for (int i = t; i < NBKT; i += 256) h[i] = 0;
  __syncthreads();
  const bool i32 = *flag != 0;
  const int e0 = blk * EPB;
  for (int i = t; i < EPB; i += 256) {
    int e = e0 + i;
    if (e < N_EDGES) atomicAdd(&h[edge_col(ei, i32, e) >> BKT_SHIFT], 1);
  }
  __syncthreads();
  for (int i = t; i < NBKT; i += 256) hist[i * NBLK + blk] = h[i];
}

// Pass 2a: per-bucket totals (tree reduce; 391-way parallel)
__global__ __launch_bounds__(256) void btot_kernel(const int* __restrict__ hist,
                                                   int* __restrict__ btot) {
  __shared__ int sh[256];
  const int b = blockIdx.x, t = threadIdx.x;
  int s = 0;
  for (int i = t; i < NBLK; i += 256) s += hist[b * NBLK + i];
  sh[t] = s;
  __syncthreads();
  for (int ofs = 128; ofs > 0; ofs >>= 1) {
    if (t < ofs) sh[t] += sh[t + ofs];
    __syncthreads();
  }
  if (t == 0) btot[b] = sh[0];
}

// Pass 2b: exclusive scan of the 391 bucket totals -> bbase (tiny serial part)
__global__ __launch_bounds__(512) void bbase_kernel(const int* __restrict__ btot,
                                                    int* __restrict__ bbase,
                                                    int* __restrict__ S) {
  __shared__ int sh[512];
  const int t = threadIdx.x;
  int v = (t < NBKT) ? btot[t] : 0;
  sh[t] = v;
  __syncthreads();
  for (int ofs = 1; ofs < 512; ofs <<= 1) {
    int u = (t >= ofs) ? sh[t - ofs] : 0;
    __syncthreads();
    sh[t] += u;
    __syncthreads();
  }
  if (t < NBKT) bbase[t] = sh[t] - v;  // exclusive
  if (t == 0) S[SCAN_M] = N_EDGES;
}

// Pass 2c: per-bucket exclusive scan over NBLK block counts + base -> S.
__global__ __launch_bounds__(256) void bscan2_kernel(const int* __restrict__ hist,
                                                     const int* __restrict__ bbase,
                                                     int* __restrict__ S) {
  __shared__ int sh[256];
  const int b = blockIdx.x, t = threadIdx.x;
  int v = (t < NBLK) ? hist[b * NBLK + t] : 0;
  sh[t] = v;
  __syncthreads();
  for (int ofs = 1; ofs < 256; ofs <<= 1) {
    int u = (t >= ofs) ? sh[t - ofs] : 0;
    __syncthreads();
    sh[t] += u;
    __syncthreads();
  }
  if (t < NBLK) S[b * NBLK + t] = bbase[b] + sh[t] - v;
}

// Pass 3: re-read edges, place {row,col} into the block's exclusive runs.
__global__ __launch_bounds__(256) void binfill_kernel(const int* __restrict__ ei,
                                                      const int* __restrict__ flag,
                                                      const int* __restrict__ S,
                                                      int2* __restrict__ bins) {
  __shared__ int cur[NBKT];
  const int t = threadIdx.x, blk = blockIdx.x;
  for (int i = t; i < NBKT; i += 256) cur[i] = S[i * NBLK + blk];
  __syncthreads();
  const bool i32 = *flag != 0;
  const int e0 = blk * EPB;
  for (int i = t; i < EPB; i += 256) {
    int e = e0 + i;
    if (e < N_EDGES) {
      int r = edge_row(ei, i32, e);
      int c = edge_col(ei, i32, e);
      int p = atomicAdd(&cur[c >> BKT_SHIFT], 1);  // LDS atomic only
      bins[p] = make_int2(r, c);
    }
  }
}

// Pass 4 (fused): per bucket, histogram+scan of bins gives dis and rptr;
// reorder rows into CSR order (LDS cursors); write erow coalesced.
__global__ __launch_bounds__(512) void degdis_scatter_kernel(
    const int2* __restrict__ bins, const int* __restrict__ S,
    float* __restrict__ dis, int* __restrict__ rptr,
    uint32_t* __restrict__ erow) {
  __shared__ int h[256];
  __shared__ int sc[256];
  __shared__ int loff[256];
  __shared__ int lcur[256];
  __shared__ uint32_t reord[BKT_CAP];
  const int b = blockIdx.x, t = threadIdx.x;
  const int Bb = S[b * NBLK];
  const int Be = S[(b + 1) * NBLK];
  const int cnt = min(Be - Bb, BKT_CAP);
  if (t < 256) h[t] = 0;
  __syncthreads();
  for (int i = t; i < cnt; i += 512)
    atomicAdd(&h[bins[Bb + i].y & 255], 1);
  __syncthreads();
  if (t < 256) sc[t] = h[t];
  __syncthreads();
  for (int ofs = 1; ofs < 256; ofs <<= 1) {
    int u = 0;
    if (t >= ofs && t < 256) u = sc[t - ofs];
    __syncthreads();
    if (t < 256) sc[t] += u;
    __syncthreads();
  }
  const int c0 = b << BKT_SHIFT;
  const int nn = min(256, N_NODES - c0);
  if (t < 256) {
    loff[t] = sc[t] - h[t];  // exclusive local offset
    lcur[t] = 0;
    if (t < nn) {
      int d = h[t];
      dis[c0 + t] = (d > 0) ? (1.0f / sqrtf((float)d)) : 0.0f;
      rptr[c0 + t] = Bb + sc[t] - d;
    }
  }
  if (b == NBKT - 1 && t == 0) rptr[N_NODES] = N_EDGES;
  __syncthreads();
  // ---- reorder edge rows into CSR order ----
  for (int i = t; i < cnt; i += 512) {
    int2 rec = bins[Bb + i];          // L2-hot re-read
    int lc = rec.y & 255;
    int p = atomicAdd(&lcur[lc], 1);
    reord[loff[lc] + p] = (uint32_t)rec.x;
  }
  __syncthreads();
  for (int i = t; i < cnt; i += 512) erow[Bb + i] = reord[i];
}

// ---------------- Weight pre-conversion f32 -> bf16 ----------------
__global__ __launch_bounds__(256) void wcvt_kernel(
    const float* __restrict__ W1, const float* __restrict__ W2,
    const float* __restrict__ W3,
    bf16_t* __restrict__ Wb1, bf16_t* __restrict__ Wb2,
    bf16_t* __restrict__ Wb3) {
  int i = blockIdx.x * 256 + threadIdx.x;
  if (i < 65536) Wb1[i] = (bf16_t)W1[i];
  if (i < 32768) Wb2[i] = (bf16_t)W2[i];
  if (i < 4096)  Wb3[i] = (bf16_t)W3[i];
}

// ---------------- MFMA matmul: y_k = h @ W_k^T (+bias into y0) ----------------
// OPERAND-SWAPPED: computes D^T = W·h^T, so each thread's 4 acc regs are 4
// CONSECUTIVE OUTPUT FEATURES of one node -> float4/bf16x4 vector stores.
// A = hi+lo bf16 split (exact), W bf16. Node frags hoisted to registers once;
// W double-buffered in the freed staging LDS, pipelined with MFMA.
template <int DIN, int LOG_DOUT, int NCH, bool YB, bool AHL>
__global__ __launch_bounds__(256) void matmul_mfma_kernel(
    const void* __restrict__ hA, const void* __restrict__ hAlo,
    const bf16_t* __restrict__ Wb, const float* __restrict__ bias,
    float* __restrict__ y0, void* __restrict__ y1,
    void* __restrict__ y2, void* __restrict__ y3) {
  constexpr int LDK = DIN + 8;
  constexpr int DOUT = 1 << LOG_DOUT;
  constexpr int KI = DIN / 32;
  __shared__ bf16_t sm[2][64 * LDK];  // A hi/lo staging -> W double-buffer
  const int m0 = blockIdx.x * 64;
  const int tid = threadIdx.x;

  // ---- Stage node tile: hi -> sm[0], lo -> sm[1] ----
  if (AHL) {
    constexpr int NL = 64 * DIN / 8 / 256;  // uint4 = 8 bf16
#pragma unroll
    for (int it = 0; it < NL; ++it) {
      int idx = tid + it * 256;
      int r = idx / (DIN / 8), cc = (idx % (DIN / 8)) * 8;
      int gm = m0 + r;
      uint4 vh = make_uint4(0, 0, 0, 0), vl = make_uint4(0, 0, 0, 0);
      if (gm < N_NODES) {
        vh = ((const uint4*)hA)[((size_t)gm * DIN + cc) >> 3];
        vl = ((const uint4*)hAlo)[((size_t)gm * DIN + cc) >> 3];
      }
      *(uint4*)&sm[0][r * LDK + cc] = vh;
      *(uint4*)&sm[1][r * LDK + cc] = vl;
    }
  } else {
    constexpr int NL = 64 * DIN / 4 / 256;
    union U4 { bf16_t b[4]; uint2 u; };
#pragma unroll
    for (int it = 0; it < NL; ++it) {
      int idx = tid + it * 256;
      int r = idx / (DIN / 4), cc = (idx % (DIN / 4)) * 4;
      int gm = m0 + r;
      float4 v = (gm < N_NODES) ? ((const float4*)hA)[((size_t)gm * DIN + cc) >> 2]
                                : make_float4(0.f, 0.f, 0.f, 0.f);
      U4 hi, lo;
      hi.b[0] = (bf16_t)v.x; lo.b[0] = (bf16_t)(v.x - (float)hi.b[0]);
      hi.b[1] = (bf16_t)v.y; lo.b[1] = (bf16_t)(v.y - (float)hi.b[1]);
      hi.b[2] = (bf16_t)v.z; lo.b[2] = (bf16_t)(v.z - (float)hi.b[2]);
      hi.b[3] = (bf16_t)v.w; lo.b[3] = (bf16_t)(v.w - (float)hi.b[3]);
      *(uint2*)&sm[0][r * LDK + cc] = hi.u;
      *(uint2*)&sm[1][r * LDK + cc] = lo.u;
    }
  }
  __syncthreads();

  const int w = tid >> 6, lane = tid & 63;
  const int wm = w & 1, wn = w >> 1;
  const int quad = lane >> 4, lr = lane & 15;

  // ---- Hoist node fragments to registers (read LDS once) ----
  bf16x8 aH[2][KI], aL[2][KI];
#pragma unroll
  for (int mt = 0; mt < 2; ++mt)
#pragma unroll
    for (int ki = 0; ki < KI; ++ki) {
      int rowa = wm * 32 + mt * 16 + lr;
      int koff = ki * 32 + quad * 8;
      aH[mt][ki] = *(const bf16x8*)&sm[0][rowa * LDK + koff];
      aL[mt][ki] = *(const bf16x8*)&sm[1][rowa * LDK + koff];
    }
  __syncthreads();  // staging LDS now free for W double-buffer

  constexpr int NLB = 64 * DIN / 8 / 256;  // uint4 loads of bf16 W
  uint4 wreg[NLB];
#pragma unroll
  for (int it = 0; it < NLB; ++it) {
    int idx = tid + it * 256;
    int r = idx / (DIN / 8), cc = (idx % (DIN / 8)) * 8;
    wreg[it] = ((const uint4*)Wb)[(((size_t)r) * DIN + cc) >> 3];
    *(uint4*)&sm[0][r * LDK + cc] = wreg[it];
  }
  __syncthreads();

  for (int nc = 0; nc < NCH; ++nc) {
    int p = nc & 1;
    if (nc + 1 < NCH) {
#pragma unroll
      for (int it = 0; it < NLB; ++it) {
        int idx = tid + it * 256;
        int r = idx / (DIN / 8), cc = (idx % (DIN / 8)) * 8;
        wreg[it] = ((const uint4*)Wb)[(((size_t)((nc + 1) * 64 + r)) * DIN + cc) >> 3];
      }
    }

    f32x4 acc[2][2] = {};  // [node-tile][feat-tile]
#pragma unroll
    for (int ki = 0; ki < KI; ++ki) {
      int koff = ki * 32 + quad * 8;
      bf16x8 bfr[2];
#pragma unroll
      for (int nt = 0; nt < 2; ++nt)
        bfr[nt] = *(const bf16x8*)&sm[p][(wn * 32 + nt * 16 + lr) * LDK + koff];
#pragma unroll
      for (int mt = 0; mt < 2; ++mt)
#pragma unroll
        for (int nt = 0; nt < 2; ++nt) {
          // swapped: D^T = W-frag (rows) x node-frag (cols)
          acc[mt][nt] = mfma16(bfr[nt], aH[mt][ki], acc[mt][nt]);
          acc[mt][nt] = mfma16(bfr[nt], aL[mt][ki], acc[mt][nt]);
        }
    }

    if (nc + 1 < NCH) {
#pragma unroll
      for (int it = 0; it < NLB; ++it) {
        int idx = tid + it * 256;
        int r = idx / (DIN / 8), cc = (idx % (DIN / 8)) * 8;
        *(uint4*)&sm[p ^ 1][r * LDK + cc] = wreg[it];
      }
    }
    __syncthreads();

    // ---- Epilogue chunk nc ----
    const int n0 = nc * 64;
#pragma unroll
    for (int mt = 0; mt < 2; ++mt) {
      int m = m0 + wm * 32 + mt * 16 + lr;
      if (m >= N_NODES) continue;
#pragma unroll
      for (int nt = 0; nt < 2; ++nt) {
        int nb = n0 + wn * 32 + nt * 16 + quad * 4;
        int k = nb >> LOG_DOUT;
        int o = nb & (DOUT - 1);
        size_t oi = (size_t)m * DOUT + o;
        if (k == 0) {
          float4 bv = *(const float4*)&bias[o];
          float4 st = make_float4(acc[mt][nt][0] + bv.x, acc[mt][nt][1] + bv.y,
                                  acc[mt][nt][2] + bv.z, acc[mt][nt][3] + bv.w);
          *(float4*)&y0[oi] = st;
        } else {
          void* yk = (k == 1) ? y1 : (k == 2) ? y2 : y3;
          if (YB) {
            bf16x4 bb;
            bb.x = (bf16_t)acc[mt][nt][0];
            bb.y = (bf16_t)acc[mt][nt][1];
            bb.z = (bf16_t)acc[mt][nt][2];
            bb.w = (bf16_t)acc[mt][nt][3];
            *(bf16x4*)((bf16_t*)yk + oi) = bb;
          } else {
            *(f32x4*)((float*)yk + oi) = acc[mt][nt];
          }
        }
      }
    }
  }
}

// ---------------- Propagation: out[c] = sum_e dis[r]*dis[c]*z[r] + add[c] ----
// Round-5 structure (best measured: 76us/prop128). NEW: all STREAMING
// accesses (erow, add, outputs) use non-temporal loads/stores so they do not
// allocate in L2 — the full 4MB/XCD stays available for the random z-gather
// working set (z reuse ~10x/line if retained). z/dis/rptr stay cached.
// OMODE: 0 = f32 out, 1 = bf16 out, 2 = bf16 hi/lo pair (outv, outv2)
// EPI: 0 = none, 1 = dropout(key1), 2 = elu then dropout(key2)
template <int D, int EPI, bool ABF, int OMODE>
__global__ __launch_bounds__(256) void prop_kernel(
    const bf16_t* __restrict__ zv, const void* __restrict__ addv,
    void* __restrict__ outv, void* __restrict__ outv2,
    const int* __restrict__ rptr, const uint32_t* __restrict__ erow,
    const float* __restrict__ dis, uint32_t k0, uint32_t k1) {
  constexpr int LPN = D / 4;        // lanes per node (4 feats/lane)
  constexpr int NPB = 256 / LPN;    // nodes per block
  const int lane = threadIdx.x % LPN;
  const int nsub = threadIdx.x / LPN;
  const int c = blockIdx.x * NPB + nsub;
  if (c >= N_NODES) return;
  const int e0 = rptr[c], e1 = rptr[c + 1];
  const float dc = dis[c];
  const bf16x4* zs = (const bf16x4*)zv;
  float a0 = 0.f, a1 = 0.f, a2 = 0.f, a3 = 0.f;

  union B4U { uint64_t u; bf16x4 b; };

  int e = e0;
  for (; e + 7 < e1; e += 8) {
    uint32_t r8[8];
#pragma unroll
    for (int j = 0; j < 8; ++j) r8[j] = __builtin_nontemporal_load(&erow[e + j]);
    float w8[8];
    bf16x4 v8[8];
#pragma unroll
    for (int j = 0; j < 8; ++j) {
      w8[j] = dis[r8[j]];
      v8[j] = zs[(size_t)r8[j] * LPN + lane];
    }
#pragma unroll
    for (int j = 0; j < 8; ++j) {
      float w = w8[j] * dc;
      a0 = fmaf(w, (float)v8[j].x, a0);
      a1 = fmaf(w, (float)v8[j].y, a1);
      a2 = fmaf(w, (float)v8[j].z, a2);
      a3 = fmaf(w, (float)v8[j].w, a3);
    }
  }
  if (e + 3 < e1) {
    uint32_t r4[4];
#pragma unroll
    for (int j = 0; j < 4; ++j) r4[j] = __builtin_nontemporal_load(&erow[e + j]);
    float w4[4];
    bf16x4 v4[4];
#pragma unroll
    for (int j = 0; j < 4; ++j) {
      w4[j] = dis[r4[j]];
      v4[j] = zs[(size_t)r4[j] * LPN + lane];
    }
#pragma unroll
    for (int j = 0; j < 4; ++j) {
      float w = w4[j] * dc;
      a0 = fmaf(w, (float)v4[j].x, a0);
      a1 = fmaf(w, (float)v4[j].y, a1);
      a2 = fmaf(w, (float)v4[j].z, a2);
      a3 = fmaf(w, (float)v4[j].w, a3);
    }
    e += 4;
  }
  for (; e < e1; ++e) {
    uint32_t r = __builtin_nontemporal_load(&erow[e]);
    float w = dis[r] * dc;
    bf16x4 t = zs[(size_t)r * LPN + lane];
    a0 = fmaf(w, (float)t.x, a0);
    a1 = fmaf(w, (float)t.y, a1);
    a2 = fmaf(w, (float)t.z, a2);
    a3 = fmaf(w, (float)t.w, a3);
  }

  const size_t pidx = (size_t)c * LPN + lane;
  const uint32_t fidx = (uint32_t)c * D + 4 * lane;
  float ax[4];
  if (ABF) {
    B4U cvt;
    cvt.u = __builtin_nontemporal_load((const uint64_t*)addv + pidx);
    ax[0] = (float)cvt.b.x; ax[1] = (float)cvt.b.y;
    ax[2] = (float)cvt.b.z; ax[3] = (float)cvt.b.w;
  } else {
    u32x4 tu = __builtin_nontemporal_load((const u32x4*)addv + pidx);
    ax[0] = __uint_as_float(tu.x); ax[1] = __uint_as_float(tu.y);
    ax[2] = __uint_as_float(tu.z); ax[3] = __uint_as_float(tu.w);
  }
  float o[4] = {a0 + ax[0], a1 + ax[1], a2 + ax[2], a3 + ax[3]};
  if (EPI == 1) {
#pragma unroll
    for (int j = 0; j < 4; ++j) o[j] *= drop_scale(fidx + j, k0, k1);
  }
  if (EPI == 2) {
#pragma unroll
    for (int j = 0; j < 4; ++j) {
      o[j] = (o[j] > 0.f) ? o[j] : expm1f(o[j]);
      o[j] *= drop_scale(fidx + j, k0, k1);
    }
  }
  if (OMODE == 0) {
    u32x4 st;
    st.x = __float_as_uint(o[0]); st.y = __float_as_uint(o[1]);
    st.z = __float_as_uint(o[2]); st.w = __float_as_uint(o[3]);
    __builtin_nontemporal_store(st, (u32x4*)outv + pidx);
  } else if (OMODE == 1) {
    B4U bv;
    bv.b.x = (bf16_t)o[0]; bv.b.y = (bf16_t)o[1];
    bv.b.z = (bf16_t)o[2]; bv.b.w = (bf16_t)o[3];
    __builtin_nontemporal_store(bv.u, (uint64_t*)outv + pidx);
  } else {
    B4U hv, lv;
    hv.b.x = (bf16_t)o[0]; hv.b.y = (bf16_t)o[1];
    hv.b.z = (bf16_t)o[2]; hv.b.w = (bf16_t)o[3];
    lv.b.x = (bf16_t)(o[0] - (float)hv.b.x);
    lv.b.y = (bf16_t)(o[1] - (float)hv.b.y);
    lv.b.z = (bf16_t)(o[2] - (float)hv.b.z);
    lv.b.w = (bf16_t)(o[3] - (float)hv.b.w);
    __builtin_nontemporal_store(hv.u, (uint64_t*)outv + pidx);
    __builtin_nontemporal_store(lv.u, (uint64_t*)outv2 + pidx);
  }
}

// ---------------- Launch ----------------
extern "C" void kernel_launch(void* const* d_in, const int* in_sizes, int n_in,
                              void* d_out, int out_size, void* d_ws, size_t ws_size,
                              hipStream_t stream) {
  const float* x  = (const float*)d_in[0];
  const int*   ei = (const int*)d_in[1];
  const float* W1 = (const float*)d_in[2];
  const float* b1 = (const float*)d_in[3];
  const float* W2 = (const float*)d_in[4];
  const float* b2 = (const float*)d_in[5];
  const float* W3 = (const float*)d_in[6];
  const float* b3 = (const float*)d_in[7];
  float* out = (float*)d_out;

  char* ws = (char*)d_ws;
  size_t off = 0;
  auto alloc = [&](size_t bytes) -> char* {
    char* p = ws + off;
    off += (bytes + 255) & ~(size_t)255;
    return p;
  };
  int*   flag   = (int*)alloc(256);
  float* dis    = (float*)alloc((size_t)N_NODES * 4);
  int*   rptr   = (int*)alloc((size_t)(N_NODES + 1) * 4);
  int*   hist   = (int*)alloc((size_t)SCAN_M * 4);
  int*   S      = (int*)alloc((size_t)(SCAN_M + 1) * 4);
  int*   btot   = (int*)alloc((size_t)NBKT * 4);
  int*   bbase  = (int*)alloc((size_t)NBKT * 4);
  uint32_t* erow = (uint32_t*)alloc((size_t)N_EDGES * 4);
  bf16_t* Wb1  = (bf16_t*)alloc(65536 * 2);
  bf16_t* Wb2  = (bf16_t*)alloc(32768 * 2);
  bf16_t* Wb3  = (bf16_t*)alloc(4096 * 2);
  float*  R0  = (float*)alloc((size_t)N_NODES * 128 * 4);  // L1 y0/out; L2 y0
  float*  R2  = (float*)alloc((size_t)N_NODES * 16 * 4);   // L3 z0 (f32)
  bf16_t* Zb0 = (bf16_t*)alloc((size_t)N_NODES * 128 * 2);
  bf16_t* Zb1 = (bf16_t*)alloc((size_t)N_NODES * 128 * 2);
  bf16_t* Bb1 = (bf16_t*)alloc((size_t)N_NODES * 128 * 2);
  bf16_t* Bb2 = (bf16_t*)alloc((size_t)N_NODES * 128 * 2);

  // Bin buffer (12.8 MB) aliases R0 (51.2 MB) — bins are dead before the
  // first matmul writes R0; single-stream ordering makes this safe.
  int2* bins = (int2*)R0;

  hipMemsetAsync(flag, 0, 256, stream);

  detect_kernel<<<8, 256, 0, stream>>>(ei, flag);
  hist_kernel<<<NBLK, 256, 0, stream>>>(ei, flag, hist);
  btot_kernel<<<NBKT, 256, 0, stream>>>(hist, btot);
  bbase_kernel<<<1, 512, 0, stream>>>(btot, bbase, S);
  bscan2_kernel<<<NBKT, 256, 0, stream>>>(hist, bbase, S);
  binfill_kernel<<<NBLK, 256, 0, stream>>>(ei, flag, S, bins);
  degdis_scatter_kernel<<<NBKT, 512, 0, stream>>>(bins, S, dis, rptr, erow);
  wcvt_kernel<<<256, 256, 0, stream>>>(W1, W2, W3, Wb1, Wb2, Wb3);

  // JAX partitionable split of key(42)=(0,42): subkey_i = threefry(key; 0, i)
  uint32_t d10, d11, d20, d21;
  threefry2x32(0u, 42u, 0u, 0u, d10, d11);  // dk1
  threefry2x32(0u, 42u, 0u, 1u, d20, d21);  // dk2

  const int MB = (N_NODES + 63) / 64;        // 1563
  const int PB128 = (N_NODES + 7) / 8;       // D=128: LPN=32, NPB=8
  const int PB64n = (N_NODES + 15) / 16;     // D=64:  LPN=16, NPB=16
  const int PB16n = (N_NODES + 63) / 64;     // D=16:  LPN=4,  NPB=64

  // ---- Layer 1 (128 -> 128): Horner out = A(A(A y3 + y2) + y1) + y0 ; dropout1
  matmul_mfma_kernel<128, 7, 8, true, false><<<MB, 256, 0, stream>>>(
      x, nullptr, Wb1, b1, R0, Bb1, Bb2, Zb0);
  prop_kernel<128, 0, true, 1><<<PB128, 256, 0, stream>>>(
      Zb0, Bb2, Zb1, nullptr, rptr, erow, dis, 0, 0);
  prop_kernel<128, 0, true, 1><<<PB128, 256, 0, stream>>>(
      Zb1, Bb1, Zb0, nullptr, rptr, erow, dis, 0, 0);
  // final hop: dropout, emit hi/lo bf16 pair for layer-2 A (Ah0=Bb2, Al0=Bb1)
  prop_kernel<128, 1, false, 2><<<PB128, 256, 0, stream>>>(
      Zb0, R0, Bb2, Bb1, rptr, erow, dis, d10, d11);

  // ---- Layer 2 (128 -> 64): A = (Bb2, Bb1) hi/lo; epilogue: elu + dropout2
  float*  R1f = R0;                                   // f32 64 (R0 dead)
  bf16_t* S0 = Zb0;                                   // bf16 64-dim slots
  bf16_t* S1 = Zb0 + (size_t)N_NODES * 64;
  bf16_t* S2 = Zb1;
  bf16_t* S3 = Zb1 + (size_t)N_NODES * 64;
  matmul_mfma_kernel<128, 6, 4, true, true><<<MB, 256, 0, stream>>>(
      Bb2, Bb1, Wb2, b2, R1f, S2, S3, S0);
  prop_kernel<64, 0, true, 1><<<PB64n, 256, 0, stream>>>(
      S0, S3, S1, nullptr, rptr, erow, dis, 0, 0);
  prop_kernel<64, 0, true, 1><<<PB64n, 256, 0, stream>>>(
      S1, S2, S0, nullptr, rptr, erow, dis, 0, 0);
  // final hop: elu+dropout, emit hi/lo for layer-3 A (Ah1=S2, Al1=S3)
  prop_kernel<64, 2, false, 2><<<PB64n, 256, 0, stream>>>(
      S0, R1f, S2, S3, rptr, erow, dis, d20, d21);

  // ---- Layer 3 (64 -> 16): A = (S2, S3) hi/lo; z1..z3 bf16, z0 f32 accumuland
  float*  z0f = R2;
  bf16_t* zb1 = Bb1;
  bf16_t* zb2 = Bb1 + (size_t)N_NODES * 16;
  bf16_t* zb3 = Bb1 + (size_t)N_NODES * 32;
  matmul_mfma_kernel<64, 4, 1, true, true><<<MB, 256, 0, stream>>>(
      S2, S3, Wb3, b3, z0f, zb1, zb2, zb3);
  prop_kernel<16, 0, true, 1><<<PB16n, 256, 0, stream>>>(
      zb3, zb2, zb2, nullptr, rptr, erow, dis, 0, 0);
  prop_kernel<16, 0, true, 1><<<PB16n, 256, 0, stream>>>(
      zb2, zb1, zb1, nullptr, rptr, erow, dis, 0, 0);
  prop_kernel<16, 0, false, 0><<<PB16n, 256, 0, stream>>>(
      zb1, z0f, out, nullptr, rptr, erow, dis, 0, 0);

  (void)in_sizes; (void)n_in; (void)out_size; (void)ws_size;
}

// Round 9
// 646.485 us; speedup vs baseline: 1.1113x; 1.1113x over previous
//
#include <hip/hip_runtime.h>
#include <stdint.h>
#include <math.h>

#define N_NODES 100000
#define N_EDGES 1600000

typedef __bf16 bf16_t;
typedef __attribute__((ext_vector_type(4))) __bf16 bf16x4;
typedef __attribute__((ext_vector_type(8))) __bf16 bf16x8;
typedef __attribute__((ext_vector_type(4))) float f32x4;

__device__ __forceinline__ f32x4 mfma16(bf16x8 a, bf16x8 b, f32x4 c) {
  return __builtin_amdgcn_mfma_f32_16x16x32_bf16(a, b, c, 0, 0, 0);
}

// ---------------- Threefry-2x32 (JAX-compatible) ----------------
__device__ __host__ __forceinline__ uint32_t rotl32(uint32_t v, int d) {
  return (v << d) | (v >> (32 - d));
}

__device__ __host__ __forceinline__ void threefry2x32(uint32_t k0, uint32_t k1,
                                                      uint32_t x0, uint32_t x1,
                                                      uint32_t& o0, uint32_t& o1) {
  uint32_t ks0 = k0, ks1 = k1, ks2 = k0 ^ k1 ^ 0x1BD11BDAu;
  x0 += ks0; x1 += ks1;
#define TF_R(r) { x0 += x1; x1 = rotl32(x1, r); x1 ^= x0; }
  TF_R(13) TF_R(15) TF_R(26) TF_R(6)
  x0 += ks1; x1 += ks2 + 1u;
  TF_R(17) TF_R(29) TF_R(16) TF_R(24)
  x0 += ks2; x1 += ks0 + 2u;
  TF_R(13) TF_R(15) TF_R(26) TF_R(6)
  x0 += ks0; x1 += ks1 + 3u;
  TF_R(17) TF_R(29) TF_R(16) TF_R(24)
  x0 += ks1; x1 += ks2 + 4u;
  TF_R(13) TF_R(15) TF_R(26) TF_R(6)
  x0 += ks2; x1 += ks0 + 5u;
#undef TF_R
  o0 = x0; o1 = x1;
}

// Partitionable-threefry dropout (JAX default): bits = o0^o1 of tf(key; 0, idx)
__device__ __forceinline__ float drop_scale(uint32_t idx, uint32_t k0, uint32_t k1) {
  uint32_t o0, o1;
  threefry2x32(k0, k1, 0u, idx, o0, o1);
  uint32_t bits = o0 ^ o1;
  float u = __uint_as_float((bits >> 9) | 0x3f800000u) - 1.0f;
  return (u < 0.5f) ? 2.0f : 0.0f;
}

// ---------------- Edge dtype detect ----------------
__global__ __launch_bounds__(256) void detect_kernel(const int* __restrict__ ei,
                                                     int* __restrict__ found_nonzero) {
  int idx = blockIdx.x * 256 + threadIdx.x;  // 0..2047
  size_t j = (size_t)idx * 781;              // < 1.6M
  if (ei[2 * j + 1] != 0) atomicOr(found_nonzero, 1);
}

__device__ __forceinline__ int edge_row(const int* ei, bool i32, int e) {
  return i32 ? ei[e] : ei[2 * (size_t)e];
}
__device__ __forceinline__ int edge_col(const int* ei, bool i32, int e) {
  return i32 ? ei[N_EDGES + e] : ei[2 * ((size_t)N_EDGES + (size_t)e)];
}

// ---------------- Graph preprocessing: counting-sort CSR build --------------
// Block-aggregated counting sort — LDS histograms + hierarchical scan give
// every block an EXCLUSIVE write range. Zero contended global atomics.
// Edge stream is compact u32 rows (erow); norm = dis[r]*dis[c] is recomputed
// in prop (bit-identical f32 mul). [Nulls established by experiment: per-node
// source sort (r7), degree-sorted node order (r6), feature slicing (r4),
// non-temporal streams (r8) — all reverted.]
#define BKT_SHIFT 8
#define NBKT 391        // ceil(100000/256) buckets of 256 dest nodes
#define BKT_CAP 6144    // max bucket size (mean 4092, sigma 64 -> +32 sigma)
#define EPB 8192        // edges per histogram/fill block
#define NBLK 196        // ceil(1.6M/8192)
#define SCAN_M (NBKT * NBLK)  // 76636

// Pass 1: per-block LDS histogram over buckets -> hist[bucket][block]
__global__ __launch_bounds__(256) void hist_kernel(const int* __restrict__ ei,
                                                   const int* __restrict__ flag,
                                                   int* __restrict__ hist) {
  __shared__ int h[NBKT];
  const int t = threadIdx.x, blk = blockIdx.x;
  for (int i = t; i < NBKT; i += 256) h[i] = 0;
  __syncthreads();
  const bool i32 = *flag != 0;
  const int e0 = blk * EPB;
  for (int i = t; i < EPB; i += 256) {
    int e = e0 + i;
    if (e < N_EDGES) atomicAdd(&h[edge_col(ei, i32, e) >> BKT_SHIFT], 1);
  }
  __syncthreads();
  for (int i = t; i < NBKT; i += 256) hist[i * NBLK + blk] = h[i];
}

// Pass 2a: per-bucket totals (tree reduce; 391-way parallel)
__global__ __launch_bounds__(256) void btot_kernel(const int* __restrict__ hist,
                                                   int* __restrict__ btot) {
  __shared__ int sh[256];
  const int b = blockIdx.x, t = threadIdx.x;
  int s = 0;
  for (int i = t; i < NBLK; i += 256) s += hist[b * NBLK + i];
  sh[t] = s;
  __syncthreads();
  for (int ofs = 128; ofs > 0; ofs >>= 1) {
    if (t < ofs) sh[t] += sh[t + ofs];
    __syncthreads();
  }
  if (t == 0) btot[b] = sh[0];
}

// Pass 2b: exclusive scan of the 391 bucket totals -> bbase (tiny serial part)
__global__ __launch_bounds__(512) void bbase_kernel(const int* __restrict__ btot,
                                                    int* __restrict__ bbase,
                                                    int* __restrict__ S) {
  __shared__ int sh[512];
  const int t = threadIdx.x;
  int v = (t < NBKT) ? btot[t] : 0;
  sh[t] = v;
  __syncthreads();
  for (int ofs = 1; ofs < 512; ofs <<= 1) {
    int u = (t >= ofs) ? sh[t - ofs] : 0;
    __syncthreads();
    sh[t] += u;
    __syncthreads();
  }
  if (t < NBKT) bbase[t] = sh[t] - v;  // exclusive
  if (t == 0) S[SCAN_M] = N_EDGES;
}

// Pass 2c: per-bucket exclusive scan over NBLK block counts + base -> S.
__global__ __launch_bounds__(256) void bscan2_kernel(const int* __restrict__ hist,
                                                     const int* __restrict__ bbase,
                                                     int* __restrict__ S) {
  __shared__ int sh[256];
  const int b = blockIdx.x, t = threadIdx.x;
  int v = (t < NBLK) ? hist[b * NBLK + t] : 0;
  sh[t] = v;
  __syncthreads();
  for (int ofs = 1; ofs < 256; ofs <<= 1) {
    int u = (t >= ofs) ? sh[t - ofs] : 0;
    __syncthreads();
    sh[t] += u;
    __syncthreads();
  }
  if (t < NBLK) S[b * NBLK + t] = bbase[b] + sh[t] - v;
}

// Pass 3: re-read edges, place {row,col} into the block's exclusive runs.
__global__ __launch_bounds__(256) void binfill_kernel(const int* __restrict__ ei,
                                                      const int* __restrict__ flag,
                                                      const int* __restrict__ S,
                                                      int2* __restrict__ bins) {
  __shared__ int cur[NBKT];
  const int t = threadIdx.x, blk = blockIdx.x;
  for (int i = t; i < NBKT; i += 256) cur[i] = S[i * NBLK + blk];
  __syncthreads();
  const bool i32 = *flag != 0;
  const int e0 = blk * EPB;
  for (int i = t; i < EPB; i += 256) {
    int e = e0 + i;
    if (e < N_EDGES) {
      int r = edge_row(ei, i32, e);
      int c = edge_col(ei, i32, e);
      int p = atomicAdd(&cur[c >> BKT_SHIFT], 1);  // LDS atomic only
      bins[p] = make_int2(r, c);
    }
  }
}

// Pass 4 (fused): per bucket, histogram+scan of bins gives dis and rptr;
// reorder rows into CSR order (LDS cursors); write erow coalesced.
__global__ __launch_bounds__(512) void degdis_scatter_kernel(
    const int2* __restrict__ bins, const int* __restrict__ S,
    float* __restrict__ dis, int* __restrict__ rptr,
    uint32_t* __restrict__ erow) {
  __shared__ int h[256];
  __shared__ int sc[256];
  __shared__ int loff[256];
  __shared__ int lcur[256];
  __shared__ uint32_t reord[BKT_CAP];
  const int b = blockIdx.x, t = threadIdx.x;
  const int Bb = S[b * NBLK];
  const int Be = S[(b + 1) * NBLK];
  const int cnt = min(Be - Bb, BKT_CAP);
  if (t < 256) h[t] = 0;
  __syncthreads();
  for (int i = t; i < cnt; i += 512)
    atomicAdd(&h[bins[Bb + i].y & 255], 1);
  __syncthreads();
  if (t < 256) sc[t] = h[t];
  __syncthreads();
  for (int ofs = 1; ofs < 256; ofs <<= 1) {
    int u = 0;
    if (t >= ofs && t < 256) u = sc[t - ofs];
    __syncthreads();
    if (t < 256) sc[t] += u;
    __syncthreads();
  }
  const int c0 = b << BKT_SHIFT;
  const int nn = min(256, N_NODES - c0);
  if (t < 256) {
    loff[t] = sc[t] - h[t];  // exclusive local offset
    lcur[t] = 0;
    if (t < nn) {
      int d = h[t];
      dis[c0 + t] = (d > 0) ? (1.0f / sqrtf((float)d)) : 0.0f;
      rptr[c0 + t] = Bb + sc[t] - d;
    }
  }
  if (b == NBKT - 1 && t == 0) rptr[N_NODES] = N_EDGES;
  __syncthreads();
  // ---- reorder edge rows into CSR order ----
  for (int i = t; i < cnt; i += 512) {
    int2 rec = bins[Bb + i];          // L2-hot re-read
    int lc = rec.y & 255;
    int p = atomicAdd(&lcur[lc], 1);
    reord[loff[lc] + p] = (uint32_t)rec.x;
  }
  __syncthreads();
  for (int i = t; i < cnt; i += 512) erow[Bb + i] = reord[i];
}

// ---------------- Weight pre-conversion f32 -> bf16 ----------------
__global__ __launch_bounds__(256) void wcvt_kernel(
    const float* __restrict__ W1, const float* __restrict__ W2,
    const float* __restrict__ W3,
    bf16_t* __restrict__ Wb1, bf16_t* __restrict__ Wb2,
    bf16_t* __restrict__ Wb3) {
  int i = blockIdx.x * 256 + threadIdx.x;
  if (i < 65536) Wb1[i] = (bf16_t)W1[i];
  if (i < 32768) Wb2[i] = (bf16_t)W2[i];
  if (i < 4096)  Wb3[i] = (bf16_t)W3[i];
}

// ---------------- MFMA matmul: y_k = h @ W_k^T (+bias into y0) ----------------
// OPERAND-SWAPPED: computes D^T = W·h^T, so each thread's 4 acc regs are 4
// CONSECUTIVE OUTPUT FEATURES of one node -> float4/bf16x4 vector stores.
// A = hi+lo bf16 split (exact), W bf16. Node frags hoisted to registers once;
// W double-buffered in the freed staging LDS, pipelined with MFMA.
template <int DIN, int LOG_DOUT, int NCH, bool YB, bool AHL>
__global__ __launch_bounds__(256) void matmul_mfma_kernel(
    const void* __restrict__ hA, const void* __restrict__ hAlo,
    const bf16_t* __restrict__ Wb, const float* __restrict__ bias,
    float* __restrict__ y0, void* __restrict__ y1,
    void* __restrict__ y2, void* __restrict__ y3) {
  constexpr int LDK = DIN + 8;
  constexpr int DOUT = 1 << LOG_DOUT;
  constexpr int KI = DIN / 32;
  __shared__ bf16_t sm[2][64 * LDK];  // A hi/lo staging -> W double-buffer
  const int m0 = blockIdx.x * 64;
  const int tid = threadIdx.x;

  // ---- Stage node tile: hi -> sm[0], lo -> sm[1] ----
  if (AHL) {
    constexpr int NL = 64 * DIN / 8 / 256;  // uint4 = 8 bf16
#pragma unroll
    for (int it = 0; it < NL; ++it) {
      int idx = tid + it * 256;
      int r = idx / (DIN / 8), cc = (idx % (DIN / 8)) * 8;
      int gm = m0 + r;
      uint4 vh = make_uint4(0, 0, 0, 0), vl = make_uint4(0, 0, 0, 0);
      if (gm < N_NODES) {
        vh = ((const uint4*)hA)[((size_t)gm * DIN + cc) >> 3];
        vl = ((const uint4*)hAlo)[((size_t)gm * DIN + cc) >> 3];
      }
      *(uint4*)&sm[0][r * LDK + cc] = vh;
      *(uint4*)&sm[1][r * LDK + cc] = vl;
    }
  } else {
    constexpr int NL = 64 * DIN / 4 / 256;
    union U4 { bf16_t b[4]; uint2 u; };
#pragma unroll
    for (int it = 0; it < NL; ++it) {
      int idx = tid + it * 256;
      int r = idx / (DIN / 4), cc = (idx % (DIN / 4)) * 4;
      int gm = m0 + r;
      float4 v = (gm < N_NODES) ? ((const float4*)hA)[((size_t)gm * DIN + cc) >> 2]
                                : make_float4(0.f, 0.f, 0.f, 0.f);
      U4 hi, lo;
      hi.b[0] = (bf16_t)v.x; lo.b[0] = (bf16_t)(v.x - (float)hi.b[0]);
      hi.b[1] = (bf16_t)v.y; lo.b[1] = (bf16_t)(v.y - (float)hi.b[1]);
      hi.b[2] = (bf16_t)v.z; lo.b[2] = (bf16_t)(v.z - (float)hi.b[2]);
      hi.b[3] = (bf16_t)v.w; lo.b[3] = (bf16_t)(v.w - (float)hi.b[3]);
      *(uint2*)&sm[0][r * LDK + cc] = hi.u;
      *(uint2*)&sm[1][r * LDK + cc] = lo.u;
    }
  }
  __syncthreads();

  const int w = tid >> 6, lane = tid & 63;
  const int wm = w & 1, wn = w >> 1;
  const int quad = lane >> 4, lr = lane & 15;

  // ---- Hoist node fragments to registers (read LDS once) ----
  bf16x8 aH[2][KI], aL[2][KI];
#pragma unroll
  for (int mt = 0; mt < 2; ++mt)
#pragma unroll
    for (int ki = 0; ki < KI; ++ki) {
      int rowa = wm * 32 + mt * 16 + lr;
      int koff = ki * 32 + quad * 8;
      aH[mt][ki] = *(const bf16x8*)&sm[0][rowa * LDK + koff];
      aL[mt][ki] = *(const bf16x8*)&sm[1][rowa * LDK + koff];
    }
  __syncthreads();  // staging LDS now free for W double-buffer

  constexpr int NLB = 64 * DIN / 8 / 256;  // uint4 loads of bf16 W
  uint4 wreg[NLB];
#pragma unroll
  for (int it = 0; it < NLB; ++it) {
    int idx = tid + it * 256;
    int r = idx / (DIN / 8), cc = (idx % (DIN / 8)) * 8;
    wreg[it] = ((const uint4*)Wb)[(((size_t)r) * DIN + cc) >> 3];
    *(uint4*)&sm[0][r * LDK + cc] = wreg[it];
  }
  __syncthreads();

  for (int nc = 0; nc < NCH; ++nc) {
    int p = nc & 1;
    if (nc + 1 < NCH) {
#pragma unroll
      for (int it = 0; it < NLB; ++it) {
        int idx = tid + it * 256;
        int r = idx / (DIN / 8), cc = (idx % (DIN / 8)) * 8;
        wreg[it] = ((const uint4*)Wb)[(((size_t)((nc + 1) * 64 + r)) * DIN + cc) >> 3];
      }
    }

    f32x4 acc[2][2] = {};  // [node-tile][feat-tile]
#pragma unroll
    for (int ki = 0; ki < KI; ++ki) {
      int koff = ki * 32 + quad * 8;
      bf16x8 bfr[2];
#pragma unroll
      for (int nt = 0; nt < 2; ++nt)
        bfr[nt] = *(const bf16x8*)&sm[p][(wn * 32 + nt * 16 + lr) * LDK + koff];
#pragma unroll
      for (int mt = 0; mt < 2; ++mt)
#pragma unroll
        for (int nt = 0; nt < 2; ++nt) {
          // swapped: D^T = W-frag (rows) x node-frag (cols)
          acc[mt][nt] = mfma16(bfr[nt], aH[mt][ki], acc[mt][nt]);
          acc[mt][nt] = mfma16(bfr[nt], aL[mt][ki], acc[mt][nt]);
        }
    }

    if (nc + 1 < NCH) {
#pragma unroll
      for (int it = 0; it < NLB; ++it) {
        int idx = tid + it * 256;
        int r = idx / (DIN / 8), cc = (idx % (DIN / 8)) * 8;
        *(uint4*)&sm[p ^ 1][r * LDK + cc] = wreg[it];
      }
    }
    __syncthreads();

    // ---- Epilogue chunk nc ----
    const int n0 = nc * 64;
#pragma unroll
    for (int mt = 0; mt < 2; ++mt) {
      int m = m0 + wm * 32 + mt * 16 + lr;
      if (m >= N_NODES) continue;
#pragma unroll
      for (int nt = 0; nt < 2; ++nt) {
        int nb = n0 + wn * 32 + nt * 16 + quad * 4;
        int k = nb >> LOG_DOUT;
        int o = nb & (DOUT - 1);
        size_t oi = (size_t)m * DOUT + o;
        if (k == 0) {
          float4 bv = *(const float4*)&bias[o];
          float4 st = make_float4(acc[mt][nt][0] + bv.x, acc[mt][nt][1] + bv.y,
                                  acc[mt][nt][2] + bv.z, acc[mt][nt][3] + bv.w);
          *(float4*)&y0[oi] = st;
        } else {
          void* yk = (k == 1) ? y1 : (k == 2) ? y2 : y3;
          if (YB) {
            bf16x4 bb;
            bb.x = (bf16_t)acc[mt][nt][0];
            bb.y = (bf16_t)acc[mt][nt][1];
            bb.z = (bf16_t)acc[mt][nt][2];
            bb.w = (bf16_t)acc[mt][nt][3];
            *(bf16x4*)((bf16_t*)yk + oi) = bb;
          } else {
            *(f32x4*)((float*)yk + oi) = acc[mt][nt];
          }
        }
      }
    }
  }
}

// ---------------- Propagation: out[c] = sum_e dis[r]*dis[c]*z[r] + add[c] ----
// Round-5 configuration — measured optimum (76us/prop128, 3.5 TB/s).
// Row-major z (bf16), 4 feats/lane, LPN = D/4 lanes per node; 8-edge groups
// keep ~24 loads in flight per thread. The 212 MB fetch is the structural
// floor: 8 XCDs x z-array L2 fill, invariant under layout/order/ILP/cache
// policy (rounds 4-8).
// OMODE: 0 = f32 out, 1 = bf16 out, 2 = bf16 hi/lo pair (outv, outv2)
// EPI: 0 = none, 1 = dropout(key1), 2 = elu then dropout(key2)
template <int D, int EPI, bool ABF, int OMODE>
__global__ __launch_bounds__(256) void prop_kernel(
    const bf16_t* __restrict__ zv, const void* __restrict__ addv,
    void* __restrict__ outv, void* __restrict__ outv2,
    const int* __restrict__ rptr, const uint32_t* __restrict__ erow,
    const float* __restrict__ dis, uint32_t k0, uint32_t k1) {
  constexpr int LPN = D / 4;        // lanes per node (4 feats/lane)
  constexpr int NPB = 256 / LPN;    // nodes per block
  const int lane = threadIdx.x % LPN;
  const int nsub = threadIdx.x / LPN;
  const int c = blockIdx.x * NPB + nsub;
  if (c >= N_NODES) return;
  const int e0 = rptr[c], e1 = rptr[c + 1];
  const float dc = dis[c];
  const bf16x4* zs = (const bf16x4*)zv;
  float a0 = 0.f, a1 = 0.f, a2 = 0.f, a3 = 0.f;

  int e = e0;
  for (; e + 7 < e1; e += 8) {
    uint32_t r8[8];
#pragma unroll
    for (int j = 0; j < 8; ++j) r8[j] = erow[e + j];
    float w8[8];
    bf16x4 v8[8];
#pragma unroll
    for (int j = 0; j < 8; ++j) {
      w8[j] = dis[r8[j]];
      v8[j] = zs[(size_t)r8[j] * LPN + lane];
    }
#pragma unroll
    for (int j = 0; j < 8; ++j) {
      float w = w8[j] * dc;
      a0 = fmaf(w, (float)v8[j].x, a0);
      a1 = fmaf(w, (float)v8[j].y, a1);
      a2 = fmaf(w, (float)v8[j].z, a2);
      a3 = fmaf(w, (float)v8[j].w, a3);
    }
  }
  if (e + 3 < e1) {
    uint32_t r4[4];
#pragma unroll
    for (int j = 0; j < 4; ++j) r4[j] = erow[e + j];
    float w4[4];
    bf16x4 v4[4];
#pragma unroll
    for (int j = 0; j < 4; ++j) {
      w4[j] = dis[r4[j]];
      v4[j] = zs[(size_t)r4[j] * LPN + lane];
    }
#pragma unroll
    for (int j = 0; j < 4; ++j) {
      float w = w4[j] * dc;
      a0 = fmaf(w, (float)v4[j].x, a0);
      a1 = fmaf(w, (float)v4[j].y, a1);
      a2 = fmaf(w, (float)v4[j].z, a2);
      a3 = fmaf(w, (float)v4[j].w, a3);
    }
    e += 4;
  }
  for (; e < e1; ++e) {
    uint32_t r = erow[e];
    float w = dis[r] * dc;
    bf16x4 t = zs[(size_t)r * LPN + lane];
    a0 = fmaf(w, (float)t.x, a0);
    a1 = fmaf(w, (float)t.y, a1);
    a2 = fmaf(w, (float)t.z, a2);
    a3 = fmaf(w, (float)t.w, a3);
  }

  const size_t pidx = (size_t)c * LPN + lane;
  const uint32_t fidx = (uint32_t)c * D + 4 * lane;
  float ax[4];
  if (ABF) {
    bf16x4 t = ((const bf16x4*)addv)[pidx];
    ax[0] = (float)t.x; ax[1] = (float)t.y; ax[2] = (float)t.z; ax[3] = (float)t.w;
  } else {
    float4 t = ((const float4*)addv)[pidx];
    ax[0] = t.x; ax[1] = t.y; ax[2] = t.z; ax[3] = t.w;
  }
  float o[4] = {a0 + ax[0], a1 + ax[1], a2 + ax[2], a3 + ax[3]};
  if (EPI == 1) {
#pragma unroll
    for (int j = 0; j < 4; ++j) o[j] *= drop_scale(fidx + j, k0, k1);
  }
  if (EPI == 2) {
#pragma unroll
    for (int j = 0; j < 4; ++j) {
      o[j] = (o[j] > 0.f) ? o[j] : expm1f(o[j]);
      o[j] *= drop_scale(fidx + j, k0, k1);
    }
  }
  if (OMODE == 0) {
    ((float4*)outv)[pidx] = make_float4(o[0], o[1], o[2], o[3]);
  } else if (OMODE == 1) {
    bf16x4 bv;
    bv.x = (bf16_t)o[0]; bv.y = (bf16_t)o[1];
    bv.z = (bf16_t)o[2]; bv.w = (bf16_t)o[3];
    ((bf16x4*)outv)[pidx] = bv;
  } else {
    bf16x4 hv, lv;
    hv.x = (bf16_t)o[0]; hv.y = (bf16_t)o[1];
    hv.z = (bf16_t)o[2]; hv.w = (bf16_t)o[3];
    lv.x = (bf16_t)(o[0] - (float)hv.x);
    lv.y = (bf16_t)(o[1] - (float)hv.y);
    lv.z = (bf16_t)(o[2] - (float)hv.z);
    lv.w = (bf16_t)(o[3] - (float)hv.w);
    ((bf16x4*)outv)[pidx] = hv;
    ((bf16x4*)outv2)[pidx] = lv;
  }
}

// ---------------- Launch ----------------
extern "C" void kernel_launch(void* const* d_in, const int* in_sizes, int n_in,
                              void* d_out, int out_size, void* d_ws, size_t ws_size,
                              hipStream_t stream) {
  const float* x  = (const float*)d_in[0];
  const int*   ei = (const int*)d_in[1];
  const float* W1 = (const float*)d_in[2];
  const float* b1 = (const float*)d_in[3];
  const float* W2 = (const float*)d_in[4];
  const float* b2 = (const float*)d_in[5];
  const float* W3 = (const float*)d_in[6];
  const float* b3 = (const float*)d_in[7];
  float* out = (float*)d_out;

  char* ws = (char*)d_ws;
  size_t off = 0;
  auto alloc = [&](size_t bytes) -> char* {
    char* p = ws + off;
    off += (bytes + 255) & ~(size_t)255;
    return p;
  };
  int*   flag   = (int*)alloc(256);
  float* dis    = (float*)alloc((size_t)N_NODES * 4);
  int*   rptr   = (int*)alloc((size_t)(N_NODES + 1) * 4);
  int*   hist   = (int*)alloc((size_t)SCAN_M * 4);
  int*   S      = (int*)alloc((size_t)(SCAN_M + 1) * 4);
  int*   btot   = (int*)alloc((size_t)NBKT * 4);
  int*   bbase  = (int*)alloc((size_t)NBKT * 4);
  uint32_t* erow = (uint32_t*)alloc((size_t)N_EDGES * 4);
  bf16_t* Wb1  = (bf16_t*)alloc(65536 * 2);
  bf16_t* Wb2  = (bf16_t*)alloc(32768 * 2);
  bf16_t* Wb3  = (bf16_t*)alloc(4096 * 2);
  float*  R0  = (float*)alloc((size_t)N_NODES * 128 * 4);  // L1 y0/out; L2 y0
  float*  R2  = (float*)alloc((size_t)N_NODES * 16 * 4);   // L3 z0 (f32)
  bf16_t* Zb0 = (bf16_t*)alloc((size_t)N_NODES * 128 * 2);
  bf16_t* Zb1 = (bf16_t*)alloc((size_t)N_NODES * 128 * 2);
  bf16_t* Bb1 = (bf16_t*)alloc((size_t)N_NODES * 128 * 2);
  bf16_t* Bb2 = (bf16_t*)alloc((size_t)N_NODES * 128 * 2);

  // Bin buffer (12.8 MB) aliases R0 (51.2 MB) — bins are dead before the
  // first matmul writes R0; single-stream ordering makes this safe.
  int2* bins = (int2*)R0;

  hipMemsetAsync(flag, 0, 256, stream);

  detect_kernel<<<8, 256, 0, stream>>>(ei, flag);
  hist_kernel<<<NBLK, 256, 0, stream>>>(ei, flag, hist);
  btot_kernel<<<NBKT, 256, 0, stream>>>(hist, btot);
  bbase_kernel<<<1, 512, 0, stream>>>(btot, bbase, S);
  bscan2_kernel<<<NBKT, 256, 0, stream>>>(hist, bbase, S);
  binfill_kernel<<<NBLK, 256, 0, stream>>>(ei, flag, S, bins);
  degdis_scatter_kernel<<<NBKT, 512, 0, stream>>>(bins, S, dis, rptr, erow);
  wcvt_kernel<<<256, 256, 0, stream>>>(W1, W2, W3, Wb1, Wb2, Wb3);

  // JAX partitionable split of key(42)=(0,42): subkey_i = threefry(key; 0, i)
  uint32_t d10, d11, d20, d21;
  threefry2x32(0u, 42u, 0u, 0u, d10, d11);  // dk1
  threefry2x32(0u, 42u, 0u, 1u, d20, d21);  // dk2

  const int MB = (N_NODES + 63) / 64;        // 1563
  const int PB128 = (N_NODES + 7) / 8;       // D=128: LPN=32, NPB=8
  const int PB64n = (N_NODES + 15) / 16;     // D=64:  LPN=16, NPB=16
  const int PB16n = (N_NODES + 63) / 64;     // D=16:  LPN=4,  NPB=64

  // ---- Layer 1 (128 -> 128): Horner out = A(A(A y3 + y2) + y1) + y0 ; dropout1
  matmul_mfma_kernel<128, 7, 8, true, false><<<MB, 256, 0, stream>>>(
      x, nullptr, Wb1, b1, R0, Bb1, Bb2, Zb0);
  prop_kernel<128, 0, true, 1><<<PB128, 256, 0, stream>>>(
      Zb0, Bb2, Zb1, nullptr, rptr, erow, dis, 0, 0);
  prop_kernel<128, 0, true, 1><<<PB128, 256, 0, stream>>>(
      Zb1, Bb1, Zb0, nullptr, rptr, erow, dis, 0, 0);
  // final hop: dropout, emit hi/lo bf16 pair for layer-2 A (Ah0=Bb2, Al0=Bb1)
  prop_kernel<128, 1, false, 2><<<PB128, 256, 0, stream>>>(
      Zb0, R0, Bb2, Bb1, rptr, erow, dis, d10, d11);

  // ---- Layer 2 (128 -> 64): A = (Bb2, Bb1) hi/lo; epilogue: elu + dropout2
  float*  R1f = R0;                                   // f32 64 (R0 dead)
  bf16_t* S0 = Zb0;                                   // bf16 64-dim slots
  bf16_t* S1 = Zb0 + (size_t)N_NODES * 64;
  bf16_t* S2 = Zb1;
  bf16_t* S3 = Zb1 + (size_t)N_NODES * 64;
  matmul_mfma_kernel<128, 6, 4, true, true><<<MB, 256, 0, stream>>>(
      Bb2, Bb1, Wb2, b2, R1f, S2, S3, S0);
  prop_kernel<64, 0, true, 1><<<PB64n, 256, 0, stream>>>(
      S0, S3, S1, nullptr, rptr, erow, dis, 0, 0);
  prop_kernel<64, 0, true, 1><<<PB64n, 256, 0, stream>>>(
      S1, S2, S0, nullptr, rptr, erow, dis, 0, 0);
  // final hop: elu+dropout, emit hi/lo for layer-3 A (Ah1=S2, Al1=S3)
  prop_kernel<64, 2, false, 2><<<PB64n, 256, 0, stream>>>(
      S0, R1f, S2, S3, rptr, erow, dis, d20, d21);

  // ---- Layer 3 (64 -> 16): A = (S2, S3) hi/lo; z1..z3 bf16, z0 f32 accumuland
  float*  z0f = R2;
  bf16_t* zb1 = Bb1;
  bf16_t* zb2 = Bb1 + (size_t)N_NODES * 16;
  bf16_t* zb3 = Bb1 + (size_t)N_NODES * 32;
  matmul_mfma_kernel<64, 4, 1, true, true><<<MB, 256, 0, stream>>>(
      S2, S3, Wb3, b3, z0f, zb1, zb2, zb3);
  prop_kernel<16, 0, true, 1><<<PB16n, 256, 0, stream>>>(
      zb3, zb2, zb2, nullptr, rptr, erow, dis, 0, 0);
  prop_kernel<16, 0, true, 1><<<PB16n, 256, 0, stream>>>(
      zb2, zb1, zb1, nullptr, rptr, erow, dis, 0, 0);
  prop_kernel<16, 0, false, 0><<<PB16n, 256, 0, stream>>>(
      zb1, z0f, out, nullptr, rptr, erow, dis, 0, 0);

  (void)in_sizes; (void)n_in; (void)out_size; (void)ws_size;
}